// Round 10
// baseline (282.233 us; speedup 1.0000x reference)
//
#include <hip/hip_runtime.h>

// LSTM autoencoder, fused, fp32 (no fp32 MFMA on CDNA4 -> VALU).
// D=64 H=16 L=8 B=4096 T=128.
//
// Mapping: wave = 1 batch, lane = gate row g = q*16+j (q: i,f,g,o; j: state).
// 1024 blocks x 256 thr = 4096 waves = 4 waves/SIMD.
//
// Round-10 = round-8 RESUBMITTED UNCHANGED (rounds 8 and 9 both died on an
// unresponsive container; kernel has never been measured. Round 7 proved
// these container drops are not kernel-induced: the identical kernel that
// "failed" in round 6 ran fine in round 7.)
// Round-8: the R5/R7 kernels were LDS-PIPE-bound (~4500 DS ops/wave; halving
// VALU in R7 changed nothing). This round drains the LDS pipe:
//  - h state lives as 16 WAVE-UNIFORM floats regathered per step with
//    v_readlane (VALU) from the 16 producer lanes. Replaces the per-step
//    LDS write + lgkmcnt(0) drain + 4 reads. No fences remain.
//  - gate dot / out-proj: v_fmac with scalar (uniform h) x VGPR (weights).
//  - encoder GEMM: x tile stays in the coalesced-prefetch VGPRs (lane-
//    distributed); values broadcast via readlane with uniform lane index
//    ((t&3)*16+dc). x never touches LDS (staging writes+2176 reads gone).
//  - Wih row reads stay in LDS (16 distinct-lane b128 reads/tile, tiny).
//  - no inline asm, no pk_fma (R7's spill source reverted).
// DS ops/wave: ~4500 -> ~1180 (gate shfls + Wih). Remaining bound: VALU.

constexpr int Dm = 64, Tm = 128, TB = 16;

__device__ __forceinline__ float fexp2(float x) {
#if __has_builtin(__builtin_amdgcn_exp2f)
  return __builtin_amdgcn_exp2f(x);
#else
  return exp2f(x);
#endif
}
__device__ __forceinline__ float frcp(float x) {
#if __has_builtin(__builtin_amdgcn_rcpf)
  return __builtin_amdgcn_rcpf(x);
#else
  return 1.0f / x;
#endif
}
__device__ __forceinline__ float tanh_(float x) {
  float xc = fminf(15.0f, fmaxf(-15.0f, x));
  float t = fexp2(2.88539008f * xc);       // e^(2x)
  return (t - 1.0f) * frcp(t + 1.0f);
}
// wave-uniform broadcast of lane l's value (VALU v_readlane, no LDS)
__device__ __forceinline__ float rlane(float v, int l) {
  return __uint_as_float(__builtin_amdgcn_readlane(__float_as_uint(v), l));
}

__global__ __launch_bounds__(256, 4)
void lstm_ae_kernel(const float* __restrict__ x,
                    const float* __restrict__ eWih, const float* __restrict__ eWhh,
                    const float* __restrict__ eBih, const float* __restrict__ eBhh,
                    const float* __restrict__ Wl,   const float* __restrict__ bl,
                    const float* __restrict__ Wf,   const float* __restrict__ bf,
                    const float* __restrict__ dWih, const float* __restrict__ dWhh,
                    const float* __restrict__ dBih, const float* __restrict__ dBhh,
                    const float* __restrict__ Wo,   const float* __restrict__ bo,
                    float* __restrict__ out)
{
  __shared__ float s_wih[64 * 68];    // enc Wih rows padded to 68 floats
  __shared__ float s_wl[128];         // Wl [8][16]
  __shared__ float s_wf[128];         // Wf [16][8]

  const int tid = threadIdx.x;
  for (int i = tid; i < 4096; i += 256) s_wih[(i >> 6) * 68 + (i & 63)] = eWih[i];
  if (tid < 128) s_wl[tid] = Wl[tid];
  else s_wf[tid - 128] = Wf[tid - 128];
  __syncthreads();   // only block-wide sync

  const int wave = tid >> 6, lane = tid & 63;
  const int q = lane >> 4, j = lane & 15;
  const int b = blockIdx.x * 4 + wave;

  // branch-free unified activation constants for THIS lane's gate:
  //   q==2 (g-gate, tanh): t=exp2(2/ln2 * x), av=(t-1)*rcp(t+1)
  //   else  (sigmoid)    : t=exp2(-1/ln2 * x), av= 1   *rcp(t+1)
  const float sAct = (q == 2) ? 2.88539008f : -1.44269504f;
  const float qgF  = (q == 2) ? 1.0f : 0.0f;
  const float cmF  = (q == 2) ? -1.0f : 1.0f;

  // encoder Whh row (per-lane, static-indexed -> registers)
  float wv[16];
  {
    const float* wrow = eWhh + lane * 16;
#pragma unroll
    for (int k = 0; k < 16; ++k) wv[k] = wrow[k];
  }
  const float biasg = eBih[lane] + eBhh[lane];

  // h as 16 wave-uniform floats; c replicated per q
  float hu[16];
#pragma unroll
  for (int k = 0; k < 16; ++k) hu[k] = 0.0f;
  float cst = 0.0f;

  const float* xb = x + (size_t)b * (Tm * Dm);
  // prefetch tile 0 (coalesced; lane l holds tile floats [r*256 + l*4 ..+3])
  float4 xs0 = *(const float4*)(xb + 0 * 256 + lane * 4);
  float4 xs1 = *(const float4*)(xb + 1 * 256 + lane * 4);
  float4 xs2 = *(const float4*)(xb + 2 * 256 + lane * 4);
  float4 xs3 = *(const float4*)(xb + 3 * 256 + lane * 4);
  float4 xn0 = xs0, xn1 = xs1, xn2 = xs2, xn3 = xs3;

  // ================= encoder =================
#pragma unroll 1
  for (int tile = 0; tile < Tm / TB; ++tile) {
    // ---- input projection: x[t][d] broadcast via readlane from xs regs ----
    float acc[TB];
#pragma unroll
    for (int t = 0; t < TB; ++t) acc[t] = biasg;
#pragma unroll 1
    for (int dc = 0; dc < 16; ++dc) {
      const float4 w4 = *(const float4*)&s_wih[lane * 68 + dc * 4];
#pragma unroll
      for (int t = 0; t < TB; ++t) {
        const float4 xr = (t < 4) ? xs0 : (t < 8) ? xs1 : (t < 12) ? xs2 : xs3;
        const int src = ((t & 3) << 4) | dc;   // wave-uniform lane index
        acc[t] = fmaf(rlane(xr.x, src), w4.x, acc[t]);
        acc[t] = fmaf(rlane(xr.y, src), w4.y, acc[t]);
        acc[t] = fmaf(rlane(xr.z, src), w4.z, acc[t]);
        acc[t] = fmaf(rlane(xr.w, src), w4.w, acc[t]);
      }
    }

    // issue next tile's loads; latency hides under the 16 recurrence steps
    if (tile < Tm / TB - 1) {
      const float* xt = xb + (tile + 1) * (TB * Dm);
      xn0 = *(const float4*)(xt + 0 * 256 + lane * 4);
      xn1 = *(const float4*)(xt + 1 * 256 + lane * 4);
      xn2 = *(const float4*)(xt + 2 * 256 + lane * 4);
      xn3 = *(const float4*)(xt + 3 * 256 + lane * 4);
    }

    // ---- recurrence over the 16 staged steps ----
#pragma unroll
    for (int tt = 0; tt < TB; ++tt) {
      float e0 = acc[tt], e1 = 0.0f;
#pragma unroll
      for (int k = 0; k < 16; k += 2) {
        e0 = fmaf(hu[k],     wv[k],     e0);
        e1 = fmaf(hu[k + 1], wv[k + 1], e1);
      }
      const float gp = e0 + e1;
      // per-lane activation of OWN gate, then exchange activated values
      const float xc = fminf(15.0f, fmaxf(-15.0f, gp));
      const float t_ = fexp2(sAct * xc);
      const float av = fmaf(qgF, t_, cmF) * frcp(t_ + 1.0f);
      const float iv = __shfl(av, j);
      const float fv = __shfl(av, 16 + j);
      const float gv = __shfl(av, 32 + j);
      const float ov = __shfl(av, 48 + j);
      cst = fmaf(fv, cst, iv * gv);
      const float hv = ov * tanh_(cst);
      // regather h as wave-uniform scalars (VALU readlane; no LDS, no fence)
#pragma unroll
      for (int k = 0; k < 16; ++k) hu[k] = rlane(hv, k);
    }
    xs0 = xn0; xs1 = xn1; xs2 = xn2; xs3 = xn3;
  }

  // ================= latent -> rep -> decoder input gate =================
  float lat[8];
#pragma unroll
  for (int l = 0; l < 8; ++l) {
    float a = bl[l];
#pragma unroll
    for (int k = 0; k < 16; ++k) a = fmaf(hu[k], s_wl[l * 16 + k], a);
    lat[l] = a;
  }
  float rep[16];
#pragma unroll
  for (int k = 0; k < 16; ++k) {
    float a = bf[k];
#pragma unroll
    for (int l = 0; l < 8; ++l) a = fmaf(lat[l], s_wf[k * 8 + l], a);
    rep[k] = a;
  }
  float dxg;
  {
    const float* dwr = dWih + lane * 16;
    float a = dBih[lane] + dBhh[lane];
#pragma unroll
    for (int k = 0; k < 16; ++k) a = fmaf(rep[k], dwr[k], a);
    dxg = a;
  }

  // ================= decoder + fused output projection =================
  {
    const float* wrow = dWhh + lane * 16;
#pragma unroll
    for (int k = 0; k < 16; ++k) wv[k] = wrow[k];
  }
  float wov[16];
  {
    const float* wrow = Wo + lane * 16;
#pragma unroll
    for (int k = 0; k < 16; ++k) wov[k] = wrow[k];
  }
  const float bog = bo[lane];

#pragma unroll
  for (int k = 0; k < 16; ++k) hu[k] = 0.0f;
  cst = 0.0f;
  float* op = out + (size_t)b * (Tm * Dm) + lane;
#pragma unroll 1
  for (int t = 0; t < Tm; ++t) {
    float e0 = dxg, e1 = 0.0f;
#pragma unroll
    for (int k = 0; k < 16; k += 2) {
      e0 = fmaf(hu[k],     wv[k],     e0);
      e1 = fmaf(hu[k + 1], wv[k + 1], e1);
    }
    const float gp = e0 + e1;
    const float xc = fminf(15.0f, fmaxf(-15.0f, gp));
    const float t_ = fexp2(sAct * xc);
    const float av = fmaf(qgF, t_, cmF) * frcp(t_ + 1.0f);
    const float iv = __shfl(av, j);
    const float fv = __shfl(av, 16 + j);
    const float gv = __shfl(av, 32 + j);
    const float ov = __shfl(av, 48 + j);
    cst = fmaf(fv, cst, iv * gv);
    const float hv = ov * tanh_(cst);
#pragma unroll
    for (int k = 0; k < 16; ++k) hu[k] = rlane(hv, k);
    // out[b][t][lane] = h_t . Wo[lane] + bo[lane]
    float o0 = bog, o1 = 0.0f;
#pragma unroll
    for (int k = 0; k < 16; k += 2) {
      o0 = fmaf(hu[k],     wov[k],     o0);
      o1 = fmaf(hu[k + 1], wov[k + 1], o1);
    }
    op[t * 64] = o0 + o1;
  }
}

extern "C" void kernel_launch(void* const* d_in, const int* in_sizes, int n_in,
                              void* d_out, int out_size, void* d_ws, size_t ws_size,
                              hipStream_t stream) {
  const float* x    = (const float*)d_in[0];
  const float* eWih = (const float*)d_in[1];
  const float* eWhh = (const float*)d_in[2];
  const float* eBih = (const float*)d_in[3];
  const float* eBhh = (const float*)d_in[4];
  const float* Wl   = (const float*)d_in[5];
  const float* bl   = (const float*)d_in[6];
  const float* Wf   = (const float*)d_in[7];
  const float* bf   = (const float*)d_in[8];
  const float* dWih = (const float*)d_in[9];
  const float* dWhh = (const float*)d_in[10];
  const float* dBih = (const float*)d_in[11];
  const float* dBhh = (const float*)d_in[12];
  const float* Wo   = (const float*)d_in[13];
  const float* bo   = (const float*)d_in[14];

  dim3 grid(1024), block(256);
  hipLaunchKernelGGL(lstm_ae_kernel, grid, block, 0, stream,
                     x, eWih, eWhh, eBih, eBhh, Wl, bl, Wf, bf,
                     dWih, dWhh, dBih, dBhh, Wo, bo, (float*)d_out);
}

// Round 11
// 209.590 us; speedup vs baseline: 1.3466x; 1.3466x over previous
//
#include <hip/hip_runtime.h>

// LSTM autoencoder, fused, fp32 (no fp32 MFMA on CDNA4 -> VALU).
// D=64 H=16 L=8 B=4096 T=128.
//
// Mapping: wave = 1 batch, lane = gate row g = q*16+j (q: i,f,g,o; j: state).
// 1024 blocks x 256 thr = 4096 waves = 4 waves/SIMD.
//
// Round-11: empirical model from R4/R5/R10: dur ~= 84us + 6.7us per 1K VALU
// instr/wave; DS ops are free (overlapped); readlane = VALU work (R10 -40%).
// So: champion R5 structure UNCHANGED (LDS h-exchange + fences, q==0 write,
// one-tile-ahead x prefetch->LDS, activate-then-exchange, deferred decoder
// store) + remove ~7.2K VALU instr/wave via packed fp32:
//  - __builtin_elementwise_fma on float2 -> v_pk_fma_f32 (NO inline asm;
//    R7's asm version carried a FETCH anomaly + regalloc perturbation).
//  - encoder GEMM: packed acc, 2 pk_fma per (dc,t): 8192 -> 4096 instr.
//  - recurrence gate dot: starts from packed acc2[tt]: 16 -> 8 pk + 3 add.
//  - decoder gate + out-proj: 32 -> 16 pk + 6 add.

constexpr int Dm = 64, Tm = 128, TB = 16;

typedef float v2f __attribute__((ext_vector_type(2)));

__device__ __forceinline__ v2f pkfma(v2f a, v2f b, v2f c) {
#if __has_builtin(__builtin_elementwise_fma)
  return __builtin_elementwise_fma(a, b, c);
#else
  v2f d; d.x = fmaf(a.x, b.x, c.x); d.y = fmaf(a.y, b.y, c.y); return d;
#endif
}

__device__ __forceinline__ float fexp2(float x) {
#if __has_builtin(__builtin_amdgcn_exp2f)
  return __builtin_amdgcn_exp2f(x);
#else
  return exp2f(x);
#endif
}
__device__ __forceinline__ float frcp(float x) {
#if __has_builtin(__builtin_amdgcn_rcpf)
  return __builtin_amdgcn_rcpf(x);
#else
  return 1.0f / x;
#endif
}
__device__ __forceinline__ float tanh_(float x) {
  float xc = fminf(15.0f, fmaxf(-15.0f, x));
  float t = fexp2(2.88539008f * xc);       // e^(2x)
  return (t - 1.0f) * frcp(t + 1.0f);
}
// compiler+hw ordering for cross-lane LDS exchange (round-2/4-proven)
__device__ __forceinline__ void ldsfence() {
  asm volatile("s_waitcnt lgkmcnt(0)" ::: "memory");
}

__global__ __launch_bounds__(256, 4)
void lstm_ae_kernel(const float* __restrict__ x,
                    const float* __restrict__ eWih, const float* __restrict__ eWhh,
                    const float* __restrict__ eBih, const float* __restrict__ eBhh,
                    const float* __restrict__ Wl,   const float* __restrict__ bl,
                    const float* __restrict__ Wf,   const float* __restrict__ bf,
                    const float* __restrict__ dWih, const float* __restrict__ dWhh,
                    const float* __restrict__ dBih, const float* __restrict__ dBhh,
                    const float* __restrict__ Wo,   const float* __restrict__ bo,
                    float* __restrict__ out)
{
  __shared__ float s_wih[64 * 68];    // enc Wih rows padded to 68 floats
  __shared__ float s_x[4][TB * Dm];   // per-wave 4KB x tile
  __shared__ float s_h[4][16];        // per-wave h broadcast
  __shared__ float s_wl[128];         // Wl [8][16]
  __shared__ float s_wf[128];         // Wf [16][8]

  const int tid = threadIdx.x;
  for (int i = tid; i < 4096; i += 256) s_wih[(i >> 6) * 68 + (i & 63)] = eWih[i];
  if (tid < 128) s_wl[tid] = Wl[tid];
  else s_wf[tid - 128] = Wf[tid - 128];
  __syncthreads();   // only block-wide sync

  const int wave = tid >> 6, lane = tid & 63;
  const int q = lane >> 4, j = lane & 15;
  const int b = blockIdx.x * 4 + wave;
  float* sxw = s_x[wave];

  // branch-free unified activation constants for THIS lane's gate:
  //   q==2 (g-gate, tanh): t=exp2(2/ln2 * x), av=(t-1)*rcp(t+1)
  //   else  (sigmoid)    : t=exp2(-1/ln2 * x), av= 1   *rcp(t+1)
  const float sAct = (q == 2) ? 2.88539008f : -1.44269504f;
  const float qgF  = (q == 2) ? 1.0f : 0.0f;
  const float cmF  = (q == 2) ? -1.0f : 1.0f;
  const v2f z2 = {0.0f, 0.0f};

  // encoder per-gate Whh row as packed pairs (registers)
  const v2f* wrp = (const v2f*)(eWhh + lane * 16);
  v2f wp0 = wrp[0], wp1 = wrp[1], wp2 = wrp[2], wp3 = wrp[3],
      wp4 = wrp[4], wp5 = wrp[5], wp6 = wrp[6], wp7 = wrp[7];
  const float biasg = eBih[lane] + eBhh[lane];

  float4 h0 = {0.f, 0.f, 0.f, 0.f}, h1 = h0, h2 = h0, h3 = h0;  // full h, replicated
  float cst = 0.0f;                                              // c[j], replicated per q
  const float* xb = x + (size_t)b * (Tm * Dm);

  // prefetch tile 0 (coalesced: 4 x 1KB per wave)
  float4 xs0 = *(const float4*)(xb + 0 * 256 + lane * 4);
  float4 xs1 = *(const float4*)(xb + 1 * 256 + lane * 4);
  float4 xs2 = *(const float4*)(xb + 2 * 256 + lane * 4);
  float4 xs3 = *(const float4*)(xb + 3 * 256 + lane * 4);

  // ================= encoder =================
#pragma unroll 1
  for (int tile = 0; tile < Tm / TB; ++tile) {
    // stage prefetched tile into LDS
    *(float4*)&sxw[0 * 256 + lane * 4] = xs0;
    *(float4*)&sxw[1 * 256 + lane * 4] = xs1;
    *(float4*)&sxw[2 * 256 + lane * 4] = xs2;
    *(float4*)&sxw[3 * 256 + lane * 4] = xs3;
    ldsfence();   // writes visible before uniform reads below

    // ---- input projection: packed acc, 2 pk_fma per (dc,t) ----
    v2f acc2[TB];
#pragma unroll
    for (int t = 0; t < TB; ++t) acc2[t] = (v2f){biasg, 0.0f};
#pragma unroll 2
    for (int dc = 0; dc < 16; ++dc) {
      const float4 w4 = *(const float4*)&s_wih[lane * 68 + dc * 4];
      const v2f wA = {w4.x, w4.y}, wB = {w4.z, w4.w};
#pragma unroll
      for (int t = 0; t < TB; ++t) {
        const float4 x4 = *(const float4*)&sxw[t * 64 + dc * 4];  // uniform bcast
        acc2[t] = pkfma((v2f){x4.x, x4.y}, wA, acc2[t]);
        acc2[t] = pkfma((v2f){x4.z, x4.w}, wB, acc2[t]);
      }
    }

    // issue next tile's loads; latency hides under the 16 recurrence steps
    if (tile < Tm / TB - 1) {
      const float* xt = xb + (tile + 1) * (TB * Dm);
      xs0 = *(const float4*)(xt + 0 * 256 + lane * 4);
      xs1 = *(const float4*)(xt + 1 * 256 + lane * 4);
      xs2 = *(const float4*)(xt + 2 * 256 + lane * 4);
      xs3 = *(const float4*)(xt + 3 * 256 + lane * 4);
    }

    // ---- recurrence over the 16 staged steps ----
#pragma unroll
    for (int tt = 0; tt < TB; ++tt) {
      v2f e0 = pkfma((v2f){h0.x, h0.y}, wp0, acc2[tt]);
      v2f e1 = pkfma((v2f){h0.z, h0.w}, wp1, z2);
      e0 = pkfma((v2f){h1.x, h1.y}, wp2, e0);
      e1 = pkfma((v2f){h1.z, h1.w}, wp3, e1);
      e0 = pkfma((v2f){h2.x, h2.y}, wp4, e0);
      e1 = pkfma((v2f){h2.z, h2.w}, wp5, e1);
      e0 = pkfma((v2f){h3.x, h3.y}, wp6, e0);
      e1 = pkfma((v2f){h3.z, h3.w}, wp7, e1);
      const float gp = (e0.x + e0.y) + (e1.x + e1.y);
      // per-lane activation of OWN gate, then exchange activated values
      const float xc = fminf(15.0f, fmaxf(-15.0f, gp));
      const float t_ = fexp2(sAct * xc);
      const float av = fmaf(qgF, t_, cmF) * frcp(t_ + 1.0f);
      const float iv = __shfl(av, j);
      const float fv = __shfl(av, 16 + j);
      const float gv = __shfl(av, 32 + j);
      const float ov = __shfl(av, 48 + j);
      cst = fmaf(fv, cst, iv * gv);
      const float hv = ov * tanh_(cst);
      if (q == 0) s_h[wave][j] = hv;
      ldsfence();   // h write -> broadcast read ordering
      h0 = *(const float4*)&s_h[wave][0];
      h1 = *(const float4*)&s_h[wave][4];
      h2 = *(const float4*)&s_h[wave][8];
      h3 = *(const float4*)&s_h[wave][12];
    }
  }

  // ================= latent -> rep -> decoder input gate (per lane) =================
  float lat[8];
#pragma unroll
  for (int l = 0; l < 8; ++l) {
    const float* wl4 = &s_wl[l * 16];
    float a = bl[l];
#pragma unroll
    for (int k = 0; k < 4; ++k) {
      const float4 wv4 = *(const float4*)&wl4[k * 4];
      const float4 hh = (k == 0) ? h0 : (k == 1) ? h1 : (k == 2) ? h2 : h3;
      a = fmaf(hh.x, wv4.x, fmaf(hh.y, wv4.y, fmaf(hh.z, wv4.z, fmaf(hh.w, wv4.w, a))));
    }
    lat[l] = a;
  }
  float rep[16];
#pragma unroll
  for (int k = 0; k < 16; ++k) {
    const float* wf8 = &s_wf[k * 8];
    float a = bf[k];
#pragma unroll
    for (int l = 0; l < 8; ++l) a = fmaf(lat[l], wf8[l], a);
    rep[k] = a;
  }
  const float* dwr = dWih + lane * 16;
  float dxg = dBih[lane] + dBhh[lane];
#pragma unroll
  for (int k = 0; k < 16; ++k) dxg = fmaf(rep[k], dwr[k], dxg);

  // ================= decoder + fused output projection =================
  {
    const v2f* dwp = (const v2f*)(dWhh + lane * 16);
    wp0 = dwp[0]; wp1 = dwp[1]; wp2 = dwp[2]; wp3 = dwp[3];
    wp4 = dwp[4]; wp5 = dwp[5]; wp6 = dwp[6]; wp7 = dwp[7];
  }
  const v2f* wop = (const v2f*)(Wo + lane * 16);
  const v2f op0 = wop[0], op1 = wop[1], op2 = wop[2], op3 = wop[3],
            op4 = wop[4], op5 = wop[5], op6 = wop[6], op7 = wop[7];
  const float bog = bo[lane];
  const v2f dx2 = {dxg, 0.0f};
  const v2f bg2 = {bog, 0.0f};

  h0 = h1 = h2 = h3 = make_float4(0.f, 0.f, 0.f, 0.f);
  cst = 0.0f;
  float* op = out + (size_t)b * (Tm * Dm) + lane;
#pragma unroll 1
  for (int t = 0; t < Tm; ++t) {
    v2f e0 = pkfma((v2f){h0.x, h0.y}, wp0, dx2);
    v2f e1 = pkfma((v2f){h0.z, h0.w}, wp1, z2);
    e0 = pkfma((v2f){h1.x, h1.y}, wp2, e0);
    e1 = pkfma((v2f){h1.z, h1.w}, wp3, e1);
    e0 = pkfma((v2f){h2.x, h2.y}, wp4, e0);
    e1 = pkfma((v2f){h2.z, h2.w}, wp5, e1);
    e0 = pkfma((v2f){h3.x, h3.y}, wp6, e0);
    e1 = pkfma((v2f){h3.z, h3.w}, wp7, e1);
    const float gp = (e0.x + e0.y) + (e1.x + e1.y);
    const float xc = fminf(15.0f, fmaxf(-15.0f, gp));
    const float t_ = fexp2(sAct * xc);
    const float av = fmaf(qgF, t_, cmF) * frcp(t_ + 1.0f);
    const float iv = __shfl(av, j);
    const float fv = __shfl(av, 16 + j);
    const float gv = __shfl(av, 32 + j);
    const float ov = __shfl(av, 48 + j);
    // independent of the shfl results: project PREVIOUS h -> out[t-1]
    v2f f0 = pkfma((v2f){h0.x, h0.y}, op0, bg2);
    v2f f1 = pkfma((v2f){h0.z, h0.w}, op1, z2);
    f0 = pkfma((v2f){h1.x, h1.y}, op2, f0);
    f1 = pkfma((v2f){h1.z, h1.w}, op3, f1);
    f0 = pkfma((v2f){h2.x, h2.y}, op4, f0);
    f1 = pkfma((v2f){h2.z, h2.w}, op5, f1);
    f0 = pkfma((v2f){h3.x, h3.y}, op6, f0);
    f1 = pkfma((v2f){h3.z, h3.w}, op7, f1);
    if (t) op[(t - 1) * 64] = (f0.x + f0.y) + (f1.x + f1.y);
    cst = fmaf(fv, cst, iv * gv);
    const float hv = ov * tanh_(cst);
    if (q == 0) s_h[wave][j] = hv;
    ldsfence();   // h write -> broadcast read ordering
    h0 = *(const float4*)&s_h[wave][0];
    h1 = *(const float4*)&s_h[wave][4];
    h2 = *(const float4*)&s_h[wave][8];
    h3 = *(const float4*)&s_h[wave][12];
  }
  // final output row
  {
    v2f f0 = pkfma((v2f){h0.x, h0.y}, op0, bg2);
    v2f f1 = pkfma((v2f){h0.z, h0.w}, op1, z2);
    f0 = pkfma((v2f){h1.x, h1.y}, op2, f0);
    f1 = pkfma((v2f){h1.z, h1.w}, op3, f1);
    f0 = pkfma((v2f){h2.x, h2.y}, op4, f0);
    f1 = pkfma((v2f){h2.z, h2.w}, op5, f1);
    f0 = pkfma((v2f){h3.x, h3.y}, op6, f0);
    f1 = pkfma((v2f){h3.z, h3.w}, op7, f1);
    op[(Tm - 1) * 64] = (f0.x + f0.y) + (f1.x + f1.y);
  }
}

extern "C" void kernel_launch(void* const* d_in, const int* in_sizes, int n_in,
                              void* d_out, int out_size, void* d_ws, size_t ws_size,
                              hipStream_t stream) {
  const float* x    = (const float*)d_in[0];
  const float* eWih = (const float*)d_in[1];
  const float* eWhh = (const float*)d_in[2];
  const float* eBih = (const float*)d_in[3];
  const float* eBhh = (const float*)d_in[4];
  const float* Wl   = (const float*)d_in[5];
  const float* bl   = (const float*)d_in[6];
  const float* Wf   = (const float*)d_in[7];
  const float* bf   = (const float*)d_in[8];
  const float* dWih = (const float*)d_in[9];
  const float* dWhh = (const float*)d_in[10];
  const float* dBih = (const float*)d_in[11];
  const float* dBhh = (const float*)d_in[12];
  const float* Wo   = (const float*)d_in[13];
  const float* bo   = (const float*)d_in[14];

  dim3 grid(1024), block(256);
  hipLaunchKernelGGL(lstm_ae_kernel, grid, block, 0, stream,
                     x, eWih, eWhh, eBih, eBhh, Wl, bl, Wf, bf,
                     dWih, dWhh, dBih, dBhh, Wo, bo, (float*)d_out);
}

// Round 13
// 131.406 us; speedup vs baseline: 2.1478x; 1.5950x over previous
//
#include <hip/hip_runtime.h>
#include <stdint.h>

// LSTM autoencoder, fused. D=64 H=16 L=8 B=4096 T=128.
// Mapping: wave = 1 batch, lane = gate row g = q*16+j. 1024 blocks x 256 thr
// = 4096 waves = 4 waves/SIMD.
//
// Round-13 = round-12 RESUBMITTED UNCHANGED (round-12 died on the flaky
// container before compile/run; rounds 7/10 proved such drops are not
// kernel-induced).
// Round-12: encoder input-projection moved to MFMA (matrix pipe was idle).
//  - xg[16t][64g] = x_tile[16x64] . WihT[64x64] as 4 gate-blocks x 2 K-chunks
//    of mfma_f32_16x16x32_bf16, split-bf16 3-product (AhBh+AhBl+AlBh) for
//    ~fp32 accuracy (err ~2^-16).
//  - B-frags (Wih hi/lo, packed bf16x2) precomputed once -> 16KB LDS.
//  - A-frags from staged x tile (stride-68) + truncation split (~80 VALU/tile).
//  - C redistributed via 4x ds_write_b128 to [gate][20] rows (reuses the
//    x-stage LDS region), recurrence reads 4 floats per 4 steps.
//  - recurrence / latent / decoder byte-identical to the R5 champion
//    (scalar fmaf, LDS h-exchange + fences, deferred decoder store).
//  - NO pk_fma anywhere (R7/R11 proved VOP3P f32 pair-alignment spills).

constexpr int Dm = 64, Tm = 128, TB = 16;

typedef __bf16 bf16x8 __attribute__((ext_vector_type(8)));
typedef float f32x4 __attribute__((ext_vector_type(4)));
typedef unsigned int u32x4 __attribute__((ext_vector_type(4)));

__device__ __forceinline__ uint32_t pk_hi(float a, float b) {
  // pack bf16(trunc(a)) low, bf16(trunc(b)) high
  return (__float_as_uint(b) & 0xFFFF0000u) | (__float_as_uint(a) >> 16);
}
__device__ __forceinline__ float trunc_bf(float a) {
  return __uint_as_float(__float_as_uint(a) & 0xFFFF0000u);
}
__device__ __forceinline__ f32x4 mfma16(bf16x8 a, bf16x8 b, f32x4 c) {
  return __builtin_amdgcn_mfma_f32_16x16x32_bf16(a, b, c, 0, 0, 0);
}

__device__ __forceinline__ float fexp2(float x) {
#if __has_builtin(__builtin_amdgcn_exp2f)
  return __builtin_amdgcn_exp2f(x);
#else
  return exp2f(x);
#endif
}
__device__ __forceinline__ float frcp(float x) {
#if __has_builtin(__builtin_amdgcn_rcpf)
  return __builtin_amdgcn_rcpf(x);
#else
  return 1.0f / x;
#endif
}
__device__ __forceinline__ float tanh_(float x) {
  float xc = fminf(15.0f, fmaxf(-15.0f, x));
  float t = fexp2(2.88539008f * xc);       // e^(2x)
  return (t - 1.0f) * frcp(t + 1.0f);
}
__device__ __forceinline__ void ldsfence() {
  asm volatile("s_waitcnt lgkmcnt(0)" ::: "memory");
}
__device__ __forceinline__ float dot4(float4 a, float4 b, float acc) {
  return fmaf(a.x, b.x, fmaf(a.y, b.y, fmaf(a.z, b.z, fmaf(a.w, b.w, acc))));
}

__global__ __launch_bounds__(256, 4)
void lstm_ae_kernel(const float* __restrict__ x,
                    const float* __restrict__ eWih, const float* __restrict__ eWhh,
                    const float* __restrict__ eBih, const float* __restrict__ eBhh,
                    const float* __restrict__ Wl,   const float* __restrict__ bl,
                    const float* __restrict__ Wf,   const float* __restrict__ bf,
                    const float* __restrict__ dWih, const float* __restrict__ dWhh,
                    const float* __restrict__ dBih, const float* __restrict__ dBhh,
                    const float* __restrict__ Wo,   const float* __restrict__ bo,
                    float* __restrict__ out)
{
  // fid = (n*2 + c)*2 + part ; part 0=hi 1=lo. frag = lane's 8 bf16 (4 dwords).
  __shared__ u32x4 s_bfrag[16][64];     // 16 KB: Wih B-fragments
  __shared__ float s_xu[4][1280];       // 20 KB: per-wave x-stage (16x68) / xg ([64][20]) union
  __shared__ float s_h[4][16];          // per-wave h broadcast
  __shared__ float s_wl[128];           // Wl [8][16]
  __shared__ float s_wf[128];           // Wf [16][8]

  const int tid = threadIdx.x;
  // ---- one-time B-fragment build (all 256 threads) ----
  {
    const int wn = tid >> 6, l = tid & 63;       // wn = gate-block n
    const int g = wn * 16 + (l & 15);            // B col -> Wih row (gate)
#pragma unroll
    for (int c = 0; c < 2; ++c) {
      const float* wp = eWih + g * 64 + c * 32 + ((l >> 4) * 8);
      const float4 wa = *(const float4*)(wp);
      const float4 wb = *(const float4*)(wp + 4);
      u32x4 hd, ld_;
      hd.x = pk_hi(wa.x, wa.y); hd.y = pk_hi(wa.z, wa.w);
      hd.z = pk_hi(wb.x, wb.y); hd.w = pk_hi(wb.z, wb.w);
      const float r0 = wa.x - trunc_bf(wa.x), r1 = wa.y - trunc_bf(wa.y);
      const float r2 = wa.z - trunc_bf(wa.z), r3 = wa.w - trunc_bf(wa.w);
      const float r4 = wb.x - trunc_bf(wb.x), r5 = wb.y - trunc_bf(wb.y);
      const float r6 = wb.z - trunc_bf(wb.z), r7 = wb.w - trunc_bf(wb.w);
      ld_.x = pk_hi(r0, r1); ld_.y = pk_hi(r2, r3);
      ld_.z = pk_hi(r4, r5); ld_.w = pk_hi(r6, r7);
      s_bfrag[(wn * 2 + c) * 2 + 0][l] = hd;
      s_bfrag[(wn * 2 + c) * 2 + 1][l] = ld_;
    }
  }
  if (tid < 128) s_wl[tid] = Wl[tid];
  else s_wf[tid - 128] = Wf[tid - 128];
  __syncthreads();   // only block-wide sync

  const int wave = tid >> 6, lane = tid & 63;
  const int q = lane >> 4, j = lane & 15;
  const int b = blockIdx.x * 4 + wave;
  float* sxw = s_xu[wave];

  // unified activation constants (q==2 -> tanh, else sigmoid)
  const float sAct = (q == 2) ? 2.88539008f : -1.44269504f;
  const float qgF  = (q == 2) ? 1.0f : 0.0f;
  const float cmF  = (q == 2) ? -1.0f : 1.0f;

  // encoder Whh row (per-lane, registers) — R5 recurrence unchanged
  const float4* wr = (const float4*)(eWhh + lane * 16);
  float4 w0 = wr[0], w1 = wr[1], w2 = wr[2], w3 = wr[3];

  // per-lane bias for gate-block columns: bv[n] = bias[n*16 + j]
  float bv0 = eBih[0 * 16 + j] + eBhh[0 * 16 + j];
  float bv1 = eBih[1 * 16 + j] + eBhh[1 * 16 + j];
  float bv2 = eBih[2 * 16 + j] + eBhh[2 * 16 + j];
  float bv3 = eBih[3 * 16 + j] + eBhh[3 * 16 + j];

  float4 h0 = {0.f, 0.f, 0.f, 0.f}, h1 = h0, h2 = h0, h3 = h0;
  float cst = 0.0f;
  const float* xb = x + (size_t)b * (Tm * Dm);

  // prefetch tile 0 (coalesced; lane holds t = 4r+(lane>>4), d = 4(lane&15)..+3)
  float4 xs0 = *(const float4*)(xb + 0 * 256 + lane * 4);
  float4 xs1 = *(const float4*)(xb + 1 * 256 + lane * 4);
  float4 xs2 = *(const float4*)(xb + 2 * 256 + lane * 4);
  float4 xs3 = *(const float4*)(xb + 3 * 256 + lane * 4);

  // ================= encoder =================
#pragma unroll 1
  for (int tile = 0; tile < Tm / TB; ++tile) {
    // ---- stage x tile, row stride 68 floats ----
    *(float4*)&sxw[(4 * 0 + q) * 68 + j * 4] = xs0;
    *(float4*)&sxw[(4 * 1 + q) * 68 + j * 4] = xs1;
    *(float4*)&sxw[(4 * 2 + q) * 68 + j * 4] = xs2;
    *(float4*)&sxw[(4 * 3 + q) * 68 + j * 4] = xs3;

    // issue next tile's loads early (regs free after the ds_writes issue)
    if (tile < Tm / TB - 1) {
      const float* xt = xb + (tile + 1) * (TB * Dm);
      xs0 = *(const float4*)(xt + 0 * 256 + lane * 4);
      xs1 = *(const float4*)(xt + 1 * 256 + lane * 4);
      xs2 = *(const float4*)(xt + 2 * 256 + lane * 4);
      xs3 = *(const float4*)(xt + 3 * 256 + lane * 4);
    }
    ldsfence();   // stage writes visible before A-frag reads

    // ---- A fragments: lane -> A[row=j][k = q*8 + e] per K-chunk ----
    const float4 xa0 = *(const float4*)&sxw[j * 68 +  0 + q * 8];
    const float4 xa1 = *(const float4*)&sxw[j * 68 +  0 + q * 8 + 4];
    const float4 xb0 = *(const float4*)&sxw[j * 68 + 32 + q * 8];
    const float4 xb1 = *(const float4*)&sxw[j * 68 + 32 + q * 8 + 4];
    u32x4 ah0u, al0u, ah1u, al1u;
    ah0u.x = pk_hi(xa0.x, xa0.y); ah0u.y = pk_hi(xa0.z, xa0.w);
    ah0u.z = pk_hi(xa1.x, xa1.y); ah0u.w = pk_hi(xa1.z, xa1.w);
    {
      const float r0 = xa0.x - trunc_bf(xa0.x), r1 = xa0.y - trunc_bf(xa0.y);
      const float r2 = xa0.z - trunc_bf(xa0.z), r3 = xa0.w - trunc_bf(xa0.w);
      const float r4 = xa1.x - trunc_bf(xa1.x), r5 = xa1.y - trunc_bf(xa1.y);
      const float r6 = xa1.z - trunc_bf(xa1.z), r7 = xa1.w - trunc_bf(xa1.w);
      al0u.x = pk_hi(r0, r1); al0u.y = pk_hi(r2, r3);
      al0u.z = pk_hi(r4, r5); al0u.w = pk_hi(r6, r7);
    }
    ah1u.x = pk_hi(xb0.x, xb0.y); ah1u.y = pk_hi(xb0.z, xb0.w);
    ah1u.z = pk_hi(xb1.x, xb1.y); ah1u.w = pk_hi(xb1.z, xb1.w);
    {
      const float r0 = xb0.x - trunc_bf(xb0.x), r1 = xb0.y - trunc_bf(xb0.y);
      const float r2 = xb0.z - trunc_bf(xb0.z), r3 = xb0.w - trunc_bf(xb0.w);
      const float r4 = xb1.x - trunc_bf(xb1.x), r5 = xb1.y - trunc_bf(xb1.y);
      const float r6 = xb1.z - trunc_bf(xb1.z), r7 = xb1.w - trunc_bf(xb1.w);
      al1u.x = pk_hi(r0, r1); al1u.y = pk_hi(r2, r3);
      al1u.z = pk_hi(r4, r5); al1u.w = pk_hi(r6, r7);
    }
    const bf16x8 Ah0 = __builtin_bit_cast(bf16x8, ah0u);
    const bf16x8 Al0 = __builtin_bit_cast(bf16x8, al0u);
    const bf16x8 Ah1 = __builtin_bit_cast(bf16x8, ah1u);
    const bf16x8 Al1 = __builtin_bit_cast(bf16x8, al1u);
    ldsfence();   // A reads fully drained before xg writes reuse the region

    // ---- 24 MFMAs: 4 gate-blocks x 2 K-chunks x 3 split products ----
#pragma unroll
    for (int n = 0; n < 4; ++n) {
      const u32x4 bh0u = *(const u32x4*)&s_bfrag[(n * 2 + 0) * 2 + 0][lane];
      const u32x4 bl0u = *(const u32x4*)&s_bfrag[(n * 2 + 0) * 2 + 1][lane];
      const u32x4 bh1u = *(const u32x4*)&s_bfrag[(n * 2 + 1) * 2 + 0][lane];
      const u32x4 bl1u = *(const u32x4*)&s_bfrag[(n * 2 + 1) * 2 + 1][lane];
      const bf16x8 Bh0 = __builtin_bit_cast(bf16x8, bh0u);
      const bf16x8 Bl0 = __builtin_bit_cast(bf16x8, bl0u);
      const bf16x8 Bh1 = __builtin_bit_cast(bf16x8, bh1u);
      const bf16x8 Bl1 = __builtin_bit_cast(bf16x8, bl1u);
      const float bvn = (n == 0) ? bv0 : (n == 1) ? bv1 : (n == 2) ? bv2 : bv3;
      f32x4 a0 = {bvn, bvn, bvn, bvn};
      f32x4 a1 = {0.f, 0.f, 0.f, 0.f};
      a0 = mfma16(Al0, Bh0, a0);
      a1 = mfma16(Al1, Bh1, a1);
      a0 = mfma16(Ah0, Bl0, a0);
      a1 = mfma16(Ah1, Bl1, a1);
      a0 = mfma16(Ah0, Bh0, a0);
      a1 = mfma16(Ah1, Bh1, a1);
      const f32x4 acc = a0 + a1;
      // lane holds xg[t = 4q + r][gate = n*16 + j] -> write [gate][20] row
      *(f32x4*)&sxw[(n * 16 + j) * 20 + 4 * q] = acc;
    }
    ldsfence();   // xg writes visible before per-gate reads

    // ---- recurrence over the 16 staged steps (R5-identical math) ----
    float4 xgv = {0.f, 0.f, 0.f, 0.f};
#pragma unroll
    for (int tt = 0; tt < TB; ++tt) {
      if ((tt & 3) == 0) xgv = *(const float4*)&sxw[lane * 20 + tt];
      const float a_in = ((tt & 3) == 0) ? xgv.x : ((tt & 3) == 1) ? xgv.y
                       : ((tt & 3) == 2) ? xgv.z : xgv.w;
      float e0 = dot4(h0, w0, a_in);
      float e1 = dot4(h1, w1, 0.0f);
      e0 = dot4(h2, w2, e0);
      e1 = dot4(h3, w3, e1);
      const float gp = e0 + e1;
      const float xc = fminf(15.0f, fmaxf(-15.0f, gp));
      const float t_ = fexp2(sAct * xc);
      const float av = fmaf(qgF, t_, cmF) * frcp(t_ + 1.0f);
      const float iv = __shfl(av, j);
      const float fv = __shfl(av, 16 + j);
      const float gv = __shfl(av, 32 + j);
      const float ov = __shfl(av, 48 + j);
      cst = fmaf(fv, cst, iv * gv);
      const float hv = ov * tanh_(cst);
      if (q == 0) s_h[wave][j] = hv;
      ldsfence();   // h write -> broadcast read ordering
      h0 = *(const float4*)&s_h[wave][0];
      h1 = *(const float4*)&s_h[wave][4];
      h2 = *(const float4*)&s_h[wave][8];
      h3 = *(const float4*)&s_h[wave][12];
    }
  }

  // ================= latent -> rep -> decoder input gate (R5-identical) =================
  float lat[8];
#pragma unroll
  for (int l = 0; l < 8; ++l) {
    const float* wl4 = &s_wl[l * 16];
    float a = bl[l];
#pragma unroll
    for (int k = 0; k < 4; ++k) {
      const float4 wv4 = *(const float4*)&wl4[k * 4];
      const float4 hh = (k == 0) ? h0 : (k == 1) ? h1 : (k == 2) ? h2 : h3;
      a = fmaf(hh.x, wv4.x, fmaf(hh.y, wv4.y, fmaf(hh.z, wv4.z, fmaf(hh.w, wv4.w, a))));
    }
    lat[l] = a;
  }
  float rep[16];
#pragma unroll
  for (int k = 0; k < 16; ++k) {
    const float* wf8 = &s_wf[k * 8];
    float a = bf[k];
#pragma unroll
    for (int l = 0; l < 8; ++l) a = fmaf(lat[l], wf8[l], a);
    rep[k] = a;
  }
  const float* dwr = dWih + lane * 16;
  float dxg = dBih[lane] + dBhh[lane];
#pragma unroll
  for (int k = 0; k < 16; ++k) dxg = fmaf(rep[k], dwr[k], dxg);

  // ================= decoder + fused output projection (R5-identical) =================
  wr = (const float4*)(dWhh + lane * 16);
  w0 = wr[0]; w1 = wr[1]; w2 = wr[2]; w3 = wr[3];
  const float4* wor = (const float4*)(Wo + lane * 16);
  const float4 o0 = wor[0], o1 = wor[1], o2 = wor[2], o3 = wor[3];
  const float bog = bo[lane];

  h0 = h1 = h2 = h3 = make_float4(0.f, 0.f, 0.f, 0.f);
  cst = 0.0f;
  float* op = out + (size_t)b * (Tm * Dm) + lane;
#pragma unroll 1
  for (int t = 0; t < Tm; ++t) {
    float e0 = dot4(h0, w0, dxg);
    float e1 = dot4(h1, w1, 0.0f);
    e0 = dot4(h2, w2, e0);
    e1 = dot4(h3, w3, e1);
    const float gp = e0 + e1;
    const float xc = fminf(15.0f, fmaxf(-15.0f, gp));
    const float t_ = fexp2(sAct * xc);
    const float av = fmaf(qgF, t_, cmF) * frcp(t_ + 1.0f);
    const float iv = __shfl(av, j);
    const float fv = __shfl(av, 16 + j);
    const float gv = __shfl(av, 32 + j);
    const float ov = __shfl(av, 48 + j);
    // independent of the shfl results: project PREVIOUS h -> out[t-1]
    float p0 = dot4(h0, o0, bog);
    float p1 = dot4(h1, o1, 0.0f);
    p0 = dot4(h2, o2, p0);
    p1 = dot4(h3, o3, p1);
    if (t) op[(t - 1) * 64] = p0 + p1;
    cst = fmaf(fv, cst, iv * gv);
    const float hv = ov * tanh_(cst);
    if (q == 0) s_h[wave][j] = hv;
    ldsfence();   // h write -> broadcast read ordering
    h0 = *(const float4*)&s_h[wave][0];
    h1 = *(const float4*)&s_h[wave][4];
    h2 = *(const float4*)&s_h[wave][8];
    h3 = *(const float4*)&s_h[wave][12];
  }
  // final output row
  float p0 = dot4(h0, o0, bog);
  float p1 = dot4(h1, o1, 0.0f);
  p0 = dot4(h2, o2, p0);
  p1 = dot4(h3, o3, p1);
  op[(Tm - 1) * 64] = p0 + p1;
}

extern "C" void kernel_launch(void* const* d_in, const int* in_sizes, int n_in,
                              void* d_out, int out_size, void* d_ws, size_t ws_size,
                              hipStream_t stream) {
  const float* x    = (const float*)d_in[0];
  const float* eWih = (const float*)d_in[1];
  const float* eWhh = (const float*)d_in[2];
  const float* eBih = (const float*)d_in[3];
  const float* eBhh = (const float*)d_in[4];
  const float* Wl   = (const float*)d_in[5];
  const float* bl   = (const float*)d_in[6];
  const float* Wf   = (const float*)d_in[7];
  const float* bf   = (const float*)d_in[8];
  const float* dWih = (const float*)d_in[9];
  const float* dWhh = (const float*)d_in[10];
  const float* dBih = (const float*)d_in[11];
  const float* dBhh = (const float*)d_in[12];
  const float* Wo   = (const float*)d_in[13];
  const float* bo   = (const float*)d_in[14];

  dim3 grid(1024), block(256);
  hipLaunchKernelGGL(lstm_ae_kernel, grid, block, 0, stream,
                     x, eWih, eWhh, eBih, eBhh, Wl, bl, Wf, bf,
                     dWih, dWhh, dBih, dBhh, Wo, bo, (float*)d_out);
}